// Round 1
// 104.078 us; speedup vs baseline: 1.0326x; 1.0326x over previous
//
#include <hip/hip_runtime.h>
#include <stdint.h>

// Problem constants (match reference setup_inputs)
#define BB   16
#define CC   64
#define LL   8192
#define OO   64
#define KK   3
#define TT   64        // positions per block tile
#define XSW  72        // xs LDS stride (bf16 elems); 67 used, pad for banks + 16B align
#define SW   200       // buf (Wt/S) LDS stride (bf16 elems); 192 used, pad breaks 16-lane clash

typedef __attribute__((ext_vector_type(8))) short short8;     // 8 bf16 = 4 VGPRs (MFMA A/B frag)
typedef __attribute__((ext_vector_type(4))) float float4_t;   // MFMA C/D frag

__device__ __forceinline__ ushort f2bf(float f) {
    uint32_t u = __float_as_uint(f);
    return (ushort)((u + 0x7FFFu + ((u >> 16) & 1u)) >> 16);  // RNE
}
__device__ __forceinline__ float bf2f(ushort h) {
    return __uint_as_float(((uint32_t)h) << 16);
}

// Single kernel: no workspace, no wt_prep. Weight transposed+converted per block
// (48 KB fp32, L2-hot). LDS: buf is time-shared (Wt -> A-frag regs -> S) so the
// block footprint is 37.5 KB -> 4 blocks/CU (was 63 KB -> 2 blocks/CU).
__global__ __launch_bounds__(256, 4) void deform_main(
    const float* __restrict__ x, const float* __restrict__ offs,
    const float* __restrict__ w, const float* __restrict__ bias,
    float* __restrict__ out) {

    __shared__ ushort buf[TT * SW];       // Wt first, then S (time-shared), [row][k*64+c]
    __shared__ ushort xs[67 * XSW];       // x tile, [pos][c], bf16
    __shared__ int    Ul[TT * KK];        // local floor index per (n,k)
    __shared__ float  W0s[TT * KK], W1s[TT * KK];

    const int tid  = threadIdx.x;
    const int bb   = blockIdx.x >> 7;     // / (LL/TT = 128)
    const int tile = blockIdx.x & 127;
    const int ts   = tile * TT;

    // ---- Phase 1a: weight fp32 [O][C][K] -> bf16 buf[f][k*64+c] ----
    // 12288 floats = 3072 float4, coalesced; 192 elems/row -> 48 float4/row (no straddle)
    {
        const float4_t* src = (const float4_t*)w;
        #pragma unroll
        for (int i = 0; i < 12; i++) {
            int idx4 = tid + i * 256;
            float4_t v = src[idx4];
            int f  = idx4 / 48;
            int e0 = (idx4 - f * 48) * 4;      // element within row, = c*3 + k
            #pragma unroll
            for (int j = 0; j < 4; j++) {
                int e = e0 + j;
                int c = e / 3;
                int k = e - c * 3;
                buf[f * SW + k * 64 + c] = f2bf(v[j]);
            }
        }
    }

    // ---- Phase 1b: x tile -> LDS (transposed, bf16). padded pos p = ts+i, i in [0,67) ----
    {
        const float* xb = x + (size_t)bb * (CC * LL);
        #pragma unroll
        for (int i = 0; i < 17; i++) {
            int idx = tid + i * 256;
            if (idx < 64 * 67) {
                int c = idx / 67;
                int p = idx - c * 67;
                int j = ts + p - 1;                 // unpadded index, reflect at edges
                if (j < 0) j = -j;
                if (j >= LL) j = 2 * LL - 2 - j;
                xs[p * XSW + c] = f2bf(xb[c * LL + j]);
            }
        }
    }

    // ---- Phase 1c: offsets -> (U, w0, w1) per (n,k) ----
    if (tid < TT * KK) {
        int n = tid / 3;
        int k = tid - n * 3;
        float off = offs[((size_t)bb * LL + ts + n) * 3 + k];
        float t0  = (float)(ts + n);
        float T   = t0 + (float)k + off;
        T = fmaxf(T, t0);
        T = fminf(T, t0 + 2.0f);
        int U = (int)floorf(T);
        if (U > LL) U = LL;                 // clip to Lp-2 = 8192
        float Uf = (float)U;
        Ul[tid]  = U - ts;                  // in [n, n+2] -> xs rows valid
        W0s[tid] = fmaxf(0.0f, 1.0f - fabsf(Uf - T));
        W1s[tid] = fmaxf(0.0f, 1.0f - fabsf(Uf + 1.0f - T));
    }
    __syncthreads();

    const int lane = tid & 63;
    const int wv   = tid >> 6;
    const int lr   = lane & 15;   // m for A-frag, n for B-frag, col for C
    const int q    = lane >> 4;   // k-quad

    // ---- A-fragments -> registers (frees buf for S). 6 x short8 = 24 VGPRs ----
    short8 a[6];
    #pragma unroll
    for (int kk = 0; kk < 6; kk++)
        a[kk] = *(const short8*)&buf[(wv * 16 + lr) * SW + kk * 32 + q * 8];
    __syncthreads();   // all A reads complete before S overwrites buf

    // ---- Phase 2: build S[n][k*64+c] = w0*xs[u][c] + w1*xs[u+1][c], bf16, into buf ----
    // 64n * 3k * 8 c-groups = 1536 tasks
    #pragma unroll
    for (int i = 0; i < 6; i++) {
        int tau = tid + i * 256;
        int g   = tau & 7;
        int nk  = tau >> 3;                 // n*3 + k
        int n   = nk / 3;
        int k   = nk - n * 3;
        int u   = Ul[nk];
        float w0 = W0s[nk], w1 = W1s[nk];
        int c0  = g * 8;
        union { uint4 v; ushort u16[8]; } r0, r1;
        r0.v = *(const uint4*)&xs[u * XSW + c0];
        r1.v = *(const uint4*)&xs[(u + 1) * XSW + c0];
        uint32_t pk[4];
        #pragma unroll
        for (int j = 0; j < 4; j++) {
            float v0 = w0 * bf2f(r0.u16[2 * j])     + w1 * bf2f(r1.u16[2 * j]);
            float v1 = w0 * bf2f(r0.u16[2 * j + 1]) + w1 * bf2f(r1.u16[2 * j + 1]);
            pk[j] = (uint32_t)f2bf(v0) | ((uint32_t)f2bf(v1) << 16);
        }
        uint4 ov;
        ov.x = pk[0]; ov.y = pk[1]; ov.z = pk[2]; ov.w = pk[3];
        *(uint4*)&buf[n * SW + k * 64 + c0] = ov;
    }
    __syncthreads();

    // ---- Phase 3: GEMM. wave w: m-tile = f in [16w,16w+16); 4 n-tiles of 16 ----
    float4_t acc0 = {0.f, 0.f, 0.f, 0.f};
    float4_t acc1 = acc0, acc2 = acc0, acc3 = acc0;

    #pragma unroll
    for (int kk = 0; kk < 6; kk++) {
        int k0 = kk * 32 + q * 8;
        short8 b0 = *(const short8*)&buf[( 0 + lr) * SW + k0];
        short8 b1 = *(const short8*)&buf[(16 + lr) * SW + k0];
        short8 b2 = *(const short8*)&buf[(32 + lr) * SW + k0];
        short8 b3 = *(const short8*)&buf[(48 + lr) * SW + k0];
        acc0 = __builtin_amdgcn_mfma_f32_16x16x32_bf16(a[kk], b0, acc0, 0, 0, 0);
        acc1 = __builtin_amdgcn_mfma_f32_16x16x32_bf16(a[kk], b1, acc1, 0, 0, 0);
        acc2 = __builtin_amdgcn_mfma_f32_16x16x32_bf16(a[kk], b2, acc2, 0, 0, 0);
        acc3 = __builtin_amdgcn_mfma_f32_16x16x32_bf16(a[kk], b3, acc3, 0, 0, 0);
    }

    // ---- Phase 4: epilogue. C/D: col = lane&15 (n), row = q*4 + r (m) ----
    const int f0 = wv * 16 + q * 4;
    float4_t bv = *(const float4_t*)&bias[f0];
    float* ob = out + ((size_t)bb * OO + f0) * LL + ts;
    #pragma unroll
    for (int r = 0; r < 4; r++) {
        float* orow = ob + (size_t)r * LL;
        orow[ 0 + lr] = acc0[r] + bv[r];
        orow[16 + lr] = acc1[r] + bv[r];
        orow[32 + lr] = acc2[r] + bv[r];
        orow[48 + lr] = acc3[r] + bv[r];
    }
}

extern "C" void kernel_launch(void* const* d_in, const int* in_sizes, int n_in,
                              void* d_out, int out_size, void* d_ws, size_t ws_size,
                              hipStream_t stream) {
    (void)d_ws; (void)ws_size;   // workspace deliberately unused (no wt_prep staging)
    const float* x    = (const float*)d_in[0];
    const float* offs = (const float*)d_in[1];
    const float* w    = (const float*)d_in[2];
    const float* bias = (const float*)d_in[3];
    float* out = (float*)d_out;

    hipLaunchKernelGGL(deform_main, dim3(BB * (LL / TT)), dim3(256), 0, stream,
                       x, offs, w, bias, out);
}

// Round 2
// 99.460 us; speedup vs baseline: 1.0805x; 1.0464x over previous
//
#include <hip/hip_runtime.h>
#include <stdint.h>

// Problem constants (match reference setup_inputs)
#define BB   16
#define CC   64
#define LL   8192
#define OO   64
#define KK   3
#define TT   64        // positions per tile
#define NT   2         // tiles per block (grid = 1024 = 4 blocks/CU co-resident)
#define XSW  72        // xs LDS stride (bf16 elems); 67 used
#define SW   200       // buf LDS stride (bf16 elems); 192 used, pad breaks 16-lane clash

typedef __attribute__((ext_vector_type(8))) short short8;     // 8 bf16 (MFMA A/B frag)
typedef __attribute__((ext_vector_type(4))) float float4_t;   // MFMA C/D frag

__device__ __forceinline__ ushort f2bf(float f) {
    uint32_t u = __float_as_uint(f);
    return (ushort)((u + 0x7FFFu + ((u >> 16) & 1u)) >> 16);  // RNE
}
__device__ __forceinline__ float bf2f(ushort h) {
    return __uint_as_float(((uint32_t)h) << 16);
}

// K-dim ordering is ck = c*3+k (NOT k*64+c): weight rows need no transpose
// (pure vectorized copy-convert of [O][C][K]); S is built in the same order.
// buf is time-shared: Wt -> (A-frags to regs) -> S(t0) -> S(t1).
__global__ __launch_bounds__(256, 4) void deform_main(
    const float* __restrict__ x, const float* __restrict__ offs,
    const float* __restrict__ w, const float* __restrict__ bias,
    float* __restrict__ out) {

    __shared__ __attribute__((aligned(16))) ushort buf[TT * SW];
    __shared__ __attribute__((aligned(16))) ushort xs[67 * XSW];   // [pos][c] bf16
    __shared__ int    Ul[TT * KK];
    __shared__ float  W0s[TT * KK], W1s[TT * KK];

    const int tid  = threadIdx.x;
    const int bb   = blockIdx.x >> 6;     // 16 batches x 64 pairs
    const int pair = blockIdx.x & 63;
    const int ts0  = pair * (TT * NT);

    const float* xb = x + (size_t)bb * (CC * LL);

    // ---- issue ALL tile-0 global loads up front (weight, x, offsets) ----
    float4_t wreg[12];
    #pragma unroll
    for (int i = 0; i < 12; i++) wreg[i] = ((const float4_t*)w)[tid + i * 256];

    float xr[17];
    #pragma unroll
    for (int i = 0; i < 17; i++) {
        int idx = tid + i * 256;
        if (idx < CC * 67) {
            int c = idx / 67, p = idx - c * 67;
            int j = ts0 + p - 1;                // reflect at edges
            if (j < 0) j = -j;
            if (j >= LL) j = 2 * LL - 2 - j;
            xr[i] = xb[c * LL + j];
        }
    }
    float offv = 0.f;
    if (tid < TT * KK) offv = offs[(size_t)bb * LL * KK + ts0 * KK + tid];

    // ---- weight fp32 -> bf16 buf[f][c*3+k] : straight copy-convert ----
    #pragma unroll
    for (int i = 0; i < 12; i++) {
        int idx4 = tid + i * 256;
        int f  = idx4 / 48;
        int e0 = (idx4 - f * 48) * 4;
        uint2 pk;
        pk.x = (uint32_t)f2bf(wreg[i].x) | ((uint32_t)f2bf(wreg[i].y) << 16);
        pk.y = (uint32_t)f2bf(wreg[i].z) | ((uint32_t)f2bf(wreg[i].w) << 16);
        *(uint2*)&buf[f * SW + e0] = pk;
    }
    // ---- xs(t0) from regs ----
    #pragma unroll
    for (int i = 0; i < 17; i++) {
        int idx = tid + i * 256;
        if (idx < CC * 67) {
            int c = idx / 67, p = idx - c * 67;
            xs[p * XSW + c] = f2bf(xr[i]);
        }
    }
    // ---- Ul/W0/W1 (t0) ----
    if (tid < TT * KK) {
        int n = tid / 3, k = tid - n * 3;
        float t0v = (float)(ts0 + n);
        float T = t0v + (float)k + offv;
        T = fmaxf(T, t0v);
        T = fminf(T, t0v + 2.0f);
        int U = (int)floorf(T);
        if (U > LL) U = LL;
        float Uf = (float)U;
        Ul[tid]  = U - ts0;
        W0s[tid] = fmaxf(0.f, 1.f - fabsf(Uf - T));
        W1s[tid] = fmaxf(0.f, 1.f - fabsf(Uf + 1.f - T));
    }
    __syncthreads();                       // B1: buf=Wt, xs, Ul ready

    const int lane = tid & 63;
    const int wv   = tid >> 6;
    const int lr   = lane & 15;
    const int q    = lane >> 4;

    short8 a[6];                           // A-frags -> regs, frees buf
    #pragma unroll
    for (int kk = 0; kk < 6; kk++)
        a[kk] = *(const short8*)&buf[(wv * 16 + lr) * SW + kk * 32 + q * 8];
    __syncthreads();                       // B2: Wt reads done, buf free

    #pragma unroll
    for (int t = 0; t < NT; t++) {
        const int ts = ts0 + t * TT;

        // ---- interp -> S[n][c*3+k] in buf. task = (n, c-group of 8): 512 tasks ----
        #pragma unroll
        for (int i = 0; i < 2; i++) {
            int tau = tid + i * 256;
            int n = tau >> 3, c0 = (tau & 7) * 8;
            uint32_t wrd[12];
            #pragma unroll
            for (int m = 0; m < 12; m++) wrd[m] = 0;
            #pragma unroll
            for (int k = 0; k < 3; k++) {
                int u = Ul[n * 3 + k];
                float w0 = W0s[n * 3 + k], w1 = W1s[n * 3 + k];
                union { uint4 v; ushort u16[8]; } r0, r1;
                r0.v = *(const uint4*)&xs[u * XSW + c0];
                r1.v = *(const uint4*)&xs[(u + 1) * XSW + c0];
                #pragma unroll
                for (int j = 0; j < 8; j++) {
                    float val = w0 * bf2f(r0.u16[j]) + w1 * bf2f(r1.u16[j]);
                    int e = j * 3 + k;            // local elem within 24-run
                    wrd[e >> 1] |= (uint32_t)f2bf(val) << ((e & 1) * 16);
                }
            }
            ushort* dst = &buf[n * SW + c0 * 3];  // 48 B contiguous, 16B-aligned
            #pragma unroll
            for (int m = 0; m < 3; m++) {
                uint4 ov;
                ov.x = wrd[4 * m]; ov.y = wrd[4 * m + 1];
                ov.z = wrd[4 * m + 2]; ov.w = wrd[4 * m + 3];
                *(uint4*)&dst[m * 8] = ov;
            }
        }

        // ---- issue next-tile global loads (hide under GEMM) ----
        float xr2[17];
        float offv2 = 0.f;
        if (t + 1 < NT) {
            const int ts1 = ts + TT;
            #pragma unroll
            for (int i = 0; i < 17; i++) {
                int idx = tid + i * 256;
                if (idx < CC * 67) {
                    int c = idx / 67, p = idx - c * 67;
                    int j = ts1 + p - 1;
                    if (j < 0) j = -j;
                    if (j >= LL) j = 2 * LL - 2 - j;
                    xr2[i] = xb[c * LL + j];
                }
            }
            if (tid < TT * KK) offv2 = offs[(size_t)bb * LL * KK + ts1 * KK + tid];
        }
        __syncthreads();                   // B3: S ready, xs free

        // ---- GEMM: wave wv -> f-tile [16wv,16wv+16), 4 n-tiles of 16 ----
        float4_t acc0 = {0.f, 0.f, 0.f, 0.f};
        float4_t acc1 = acc0, acc2 = acc0, acc3 = acc0;
        #pragma unroll
        for (int kk = 0; kk < 6; kk++) {
            int k0 = kk * 32 + q * 8;
            short8 b0 = *(const short8*)&buf[( 0 + lr) * SW + k0];
            short8 b1 = *(const short8*)&buf[(16 + lr) * SW + k0];
            short8 b2 = *(const short8*)&buf[(32 + lr) * SW + k0];
            short8 b3 = *(const short8*)&buf[(48 + lr) * SW + k0];
            acc0 = __builtin_amdgcn_mfma_f32_16x16x32_bf16(a[kk], b0, acc0, 0, 0, 0);
            acc1 = __builtin_amdgcn_mfma_f32_16x16x32_bf16(a[kk], b1, acc1, 0, 0, 0);
            acc2 = __builtin_amdgcn_mfma_f32_16x16x32_bf16(a[kk], b2, acc2, 0, 0, 0);
            acc3 = __builtin_amdgcn_mfma_f32_16x16x32_bf16(a[kk], b3, acc3, 0, 0, 0);
        }

        // ---- while GEMM drains: write xs(t+1), Ul(t+1) (xs free since B3) ----
        if (t + 1 < NT) {
            const int ts1 = ts + TT;
            #pragma unroll
            for (int i = 0; i < 17; i++) {
                int idx = tid + i * 256;
                if (idx < CC * 67) {
                    int c = idx / 67, p = idx - c * 67;
                    xs[p * XSW + c] = f2bf(xr2[i]);
                }
            }
            if (tid < TT * KK) {
                int n = tid / 3, k = tid - n * 3;
                float t0v = (float)(ts1 + n);
                float T = t0v + (float)k + offv2;
                T = fmaxf(T, t0v);
                T = fminf(T, t0v + 2.0f);
                int U = (int)floorf(T);
                if (U > LL) U = LL;
                float Uf = (float)U;
                Ul[tid]  = U - ts1;
                W0s[tid] = fmaxf(0.f, 1.f - fabsf(Uf - T));
                W1s[tid] = fmaxf(0.f, 1.f - fabsf(Uf + 1.f - T));
            }
        }

        // ---- epilogue tile t. C/D: col = lane&15 (n), row = q*4 + r (m) ----
        const int f0 = wv * 16 + q * 4;
        float4_t bv = *(const float4_t*)&bias[f0];
        float* ob = out + ((size_t)bb * OO + f0) * LL + ts;
        #pragma unroll
        for (int r = 0; r < 4; r++) {
            float* orow = ob + (size_t)r * LL;
            orow[ 0 + lr] = acc0[r] + bv[r];
            orow[16 + lr] = acc1[r] + bv[r];
            orow[32 + lr] = acc2[r] + bv[r];
            orow[48 + lr] = acc3[r] + bv[r];
        }
        __syncthreads();                   // B4: buf reads done; xs(t+1)/Ul(t+1) visible
    }
}

extern "C" void kernel_launch(void* const* d_in, const int* in_sizes, int n_in,
                              void* d_out, int out_size, void* d_ws, size_t ws_size,
                              hipStream_t stream) {
    (void)d_ws; (void)ws_size;
    const float* x    = (const float*)d_in[0];
    const float* offs = (const float*)d_in[1];
    const float* w    = (const float*)d_in[2];
    const float* bias = (const float*)d_in[3];
    float* out = (float*)d_out;

    hipLaunchKernelGGL(deform_main, dim3(BB * (LL / (TT * NT))), dim3(256), 0, stream,
                       x, offs, w, bias, out);
}